// Round 1
// 2757.012 us; speedup vs baseline: 10.4721x; 10.4721x over previous
//
#include <hip/hip_runtime.h>

// ---------------------------------------------------------------------------
// WorldModelGRU (gfx950) — ROUND 7: split-bf16 MFMA rewrite.
// r6 established: fp32 in/out, I/O geometry exact, passes at absmax 0.00195.
// r6 counters: MfmaUtil=0, VALUBusy 32%, 20 TF fp32-VALU (13% of vector peak,
// <1% of matrix peak). This round moves all GEMMs to mfma_f32_16x16x32_bf16
// with hi/lo bf16 operand splitting (Ah*Bh + Ah*Bl + Al*Bh, fp32 accum) ->
// ~fp32 accuracy (dropped AlBl ~ 2^-16 rel) at MFMA rate.
//  - fused GRU cell: one kernel per cell, 128x64 tile, 8 waves, 4 gate accs
//  - token proj folded: P = emb @ W_tp^T + b_tp precomputed once; layer-0
//    input is a row-gather of P inside staging (kills 15 GEMMs)
//  - h state kept as bf16 hi/lo pairs; fp32 reconstructed as hi+lo (2^-17)
//  - LDS XOR-swizzle (16B chunks) -> <=2-way bank conflicts
// Workspace: 72.35 MB (< 75.5 MB verified in r5).
// ---------------------------------------------------------------------------

#define BB 4096
#define HH 512
#define TT 16
#define LL 3
#define BHs ((size_t)BB * HH)

typedef unsigned short u16;
typedef __attribute__((ext_vector_type(8))) short short8v;  // 8 bf16 (4 VGPR)
typedef __attribute__((ext_vector_type(4))) float f32x4;

#define MFMA16(a, b, c) __builtin_amdgcn_mfma_f32_16x16x32_bf16((a), (b), (c), 0, 0, 0)

__device__ __forceinline__ u16 f2bf(float x) {
    unsigned u = __float_as_uint(x);
    u += 0x7fffu + ((u >> 16) & 1u);          // RNE
    return (u16)(u >> 16);
}
__device__ __forceinline__ float bf2f(u16 h) {
    return __uint_as_float(((unsigned)h) << 16);
}
__device__ __forceinline__ float bf2f_s(short h) { return bf2f((u16)h); }

// ---------------------------------------------------------------------------
// fp32 -> (hi, lo) bf16 split, 4 elems/thread.  n must be a multiple of 1024.
// ---------------------------------------------------------------------------
__global__ __launch_bounds__(256) void k_split(const float* __restrict__ src,
                                               u16* __restrict__ hi,
                                               u16* __restrict__ lo)
{
    size_t i = ((size_t)blockIdx.x * 256 + threadIdx.x) * 4;
    float4 v = *(const float4*)(src + i);
    float xs[4] = {v.x, v.y, v.z, v.w};
    u16 h4[4], l4[4];
    #pragma unroll
    for (int k = 0; k < 4; k++) {
        h4[k] = f2bf(xs[k]);
        l4[k] = f2bf(xs[k] - bf2f(h4[k]));
    }
    ushort4 hv; hv.x = h4[0]; hv.y = h4[1]; hv.z = h4[2]; hv.w = h4[3];
    ushort4 lv; lv.x = l4[0]; lv.y = l4[1]; lv.z = l4[2]; lv.w = l4[3];
    *(ushort4*)(hi + i) = hv;
    *(ushort4*)(lo + i) = lv;
}

// ---------------------------------------------------------------------------
// fp32 VALU GEMM (kept from r6, used ONCE for P = emb @ W_tp^T + b_tp).
// out[b*rstride + j] = sum_k A[b,k]*W[j,k] + bias[j]
// ---------------------------------------------------------------------------
__global__ __launch_bounds__(256) void v_gemm(
    const float* __restrict__ A,
    const float* __restrict__ W,
    const float* __restrict__ bias,
    float* __restrict__ out, long rstride)
{
    const int rowBase = blockIdx.x * 64;
    const int colBase = blockIdx.y * 64;
    const int tid = threadIdx.x;
    const int tx = tid & 15;
    const int ty = tid >> 4;

    __shared__ float As[64][17];
    __shared__ float Bs[64][17];

    float acc[4][4];
    #pragma unroll
    for (int r = 0; r < 4; r++)
        #pragma unroll
        for (int c = 0; c < 4; c++)
            acc[r][c] = 0.f;

    for (int k0 = 0; k0 < HH; k0 += 16) {
        int row = tid >> 2;
        int kb  = (tid & 3) * 4;
        const float4 va = *(const float4*)(A + (size_t)(rowBase + row) * HH + k0 + kb);
        const float4 vw = *(const float4*)(W + (size_t)(colBase + row) * HH + k0 + kb);
        As[row][kb + 0] = va.x; As[row][kb + 1] = va.y;
        As[row][kb + 2] = va.z; As[row][kb + 3] = va.w;
        Bs[row][kb + 0] = vw.x; Bs[row][kb + 1] = vw.y;
        Bs[row][kb + 2] = vw.z; Bs[row][kb + 3] = vw.w;
        __syncthreads();

        #pragma unroll
        for (int k = 0; k < 16; k++) {
            float a[4], w[4];
            #pragma unroll
            for (int r = 0; r < 4; r++) a[r] = As[ty * 4 + r][k];
            #pragma unroll
            for (int c = 0; c < 4; c++) w[c] = Bs[tx * 4 + c][k];
            #pragma unroll
            for (int r = 0; r < 4; r++)
                #pragma unroll
                for (int c = 0; c < 4; c++)
                    acc[r][c] += a[r] * w[c];
        }
        __syncthreads();
    }

    #pragma unroll
    for (int r = 0; r < 4; r++) {
        int b = rowBase + ty * 4 + r;
        #pragma unroll
        for (int c = 0; c < 4; c++) {
            int j = colBase + tx * 4 + c;
            out[(long)b * rstride + j] = acc[r][c] + bias[j];
        }
    }
}

// ---------------------------------------------------------------------------
// Fused split-bf16 MFMA GRU cell.
// Tile: 128 batch rows x 64 H cols; grid (32, 8) = 256 blocks (1/CU); 512 thr
// = 8 waves (wr = wid>>2 in {0,1} row half, wc = wid&3 col quarter of 16).
// Accumulators per wave: 4 gates (r,z,i_n,h_n) x 4 row-frags x f32x4.
// r/z accumulate BOTH X@Wih and Hp@Whh MFMAs (the sum the epilogue needs).
// XMODE: 0 = X from hi/lo pair ptrs; 1 = X==0 (scan step 0); 2 = X = P[gt];
//        3 = X = action @ W_a^T + b_a computed in staging (transition step).
// LDS (u16): X_hi[0,4096) X_lo[4096) H_hi[8192) H_lo[12288)
//            W planes [16384 + p*2048), p = 0..11:
//            0..5 = {Wih_r,Wih_z,Wih_n,Whh_r,Whh_z,Whh_n} HI, 6..11 same LO.
// Tile row = 32 u16 (64 B); 16B chunks XOR-swizzled: ch ^= (row>>1)&3
// -> <=2-way bank conflict on ds_read_b128/ds_write_b128 (free, m136).
// ---------------------------------------------------------------------------
template <int XMODE>
__global__ __launch_bounds__(512, 2) void k_cell(
    const u16* __restrict__ Xhi, const u16* __restrict__ Xlo,
    const int* __restrict__ gt, int tok,
    const float* __restrict__ action, const float* __restrict__ W_a,
    const float* __restrict__ b_a,
    const u16* __restrict__ Wih_hi, const u16* __restrict__ Wih_lo,
    const u16* __restrict__ Whh_hi, const u16* __restrict__ Whh_lo,
    const float* __restrict__ bih, const float* __restrict__ bhh,
    const u16* __restrict__ Hin,   // pair: lo at +BHs
    u16* __restrict__ Hout)        // pair: lo at +BHs
{
    const int tid = threadIdx.x;
    const int lane = tid & 63;
    const int wid = tid >> 6;
    const int wr = wid >> 2;
    const int wc = wid & 3;
    const int rowBase = blockIdx.x * 128;
    const int colBase = blockIdx.y * 64;

    __shared__ u16 lds[40960];   // 80 KiB

    // ---- staging setup: X/H tiles = 128 rows x 4 chunks, 1 chunk/thread ----
    const int srow = tid >> 2;
    const int sch = tid & 3;
    const int xoff = srow * 32 + ((sch ^ ((srow >> 1) & 3)) * 8);

    const u16* xsrc_hi = nullptr;
    const u16* xsrc_lo = nullptr;
    if (XMODE == 0) {
        xsrc_hi = Xhi + (size_t)(rowBase + srow) * HH + sch * 8;
        xsrc_lo = Xlo + (size_t)(rowBase + srow) * HH + sch * 8;
    } else if (XMODE == 2) {
        size_t gr = (size_t)gt[(rowBase + srow) * TT + tok];
        xsrc_hi = Xhi + gr * HH + sch * 8;
        xsrc_lo = Xlo + gr * HH + sch * 8;
    }
    const u16* hsrc_hi = Hin + (size_t)(rowBase + srow) * HH + sch * 8;
    const u16* hsrc_lo = hsrc_hi + BHs;

    float a0 = 0.f, a1 = 0.f, a2 = 0.f;
    if (XMODE == 3) {
        a0 = action[(rowBase + srow) * 3 + 0];
        a1 = action[(rowBase + srow) * 3 + 1];
        a2 = action[(rowBase + srow) * 3 + 2];
    }

    // W staging: 12 planes x 256 chunks = 3072 chunks / 512 thr = 6 each
    const u16* wsrc[6];
    int wdst[6];
    #pragma unroll
    for (int i = 0; i < 6; i++) {
        int c = i * 512 + tid;
        int p = c >> 8;           // plane 0..11
        int q = c & 255;
        int j = q >> 2;           // block-local col 0..63
        int ch = q & 3;
        int phys = (p < 6) ? p : p - 6;
        int g = phys % 3;         // gate r/z/n
        const u16* base;
        if (p < 6) base = (phys < 3) ? Wih_hi : Whh_hi;
        else       base = (phys < 3) ? Wih_lo : Whh_lo;
        wsrc[i] = base + (size_t)(g * HH + colBase + j) * HH + ch * 8;
        wdst[i] = 16384 + p * 2048 + j * 32 + ((ch ^ ((j >> 1) & 3)) * 8);
    }

    // ---- fragment read offsets ----
    const int fcol = lane & 15;
    const int kg = lane >> 4;
    const int fj = wc * 16 + fcol;
    int woff[12];
    #pragma unroll
    for (int p = 0; p < 12; p++)
        woff[p] = 16384 + p * 2048 + fj * 32 + ((kg ^ ((fj >> 1) & 3)) * 8);
    int aoff[4];
    #pragma unroll
    for (int m = 0; m < 4; m++) {
        int r = wr * 64 + m * 16 + fcol;
        aoff[m] = r * 32 + ((kg ^ ((r >> 1) & 3)) * 8);
    }

    f32x4 accR[4], accZ[4], accNi[4], accNh[4];
    #pragma unroll
    for (int m = 0; m < 4; m++) {
        accR[m] = (f32x4){0.f, 0.f, 0.f, 0.f};
        accZ[m] = accR[m];
        accNi[m] = accR[m];
        accNh[m] = accR[m];
    }

    short8v rxh = {}, rxl = {}, rhh = {}, rhl = {}, rw[6];

    auto load_g = [&](int K0) {
        if (XMODE == 0 || XMODE == 2) {
            rxh = *(const short8v*)(xsrc_hi + K0);
            rxl = *(const short8v*)(xsrc_lo + K0);
        } else if (XMODE == 3) {
            short8v th, tl;
            #pragma unroll
            for (int kk = 0; kk < 8; kk++) {
                int k = K0 + sch * 8 + kk;
                float xv = a0 * W_a[k * 3 + 0] + a1 * W_a[k * 3 + 1] +
                           a2 * W_a[k * 3 + 2] + b_a[k];
                u16 hb = f2bf(xv);
                th[kk] = (short)hb;
                tl[kk] = (short)f2bf(xv - bf2f(hb));
            }
            rxh = th; rxl = tl;
        }
        rhh = *(const short8v*)(hsrc_hi + K0);
        rhl = *(const short8v*)(hsrc_lo + K0);
        #pragma unroll
        for (int i = 0; i < 6; i++) rw[i] = *(const short8v*)(wsrc[i] + K0);
    };
    auto write_l = [&]() {
        if (XMODE != 1) {
            *(short8v*)&lds[xoff] = rxh;
            *(short8v*)&lds[4096 + xoff] = rxl;
        }
        *(short8v*)&lds[8192 + xoff] = rhh;
        *(short8v*)&lds[12288 + xoff] = rhl;
        #pragma unroll
        for (int i = 0; i < 6; i++) *(short8v*)&lds[wdst[i]] = rw[i];
    };

    load_g(0);
    for (int k0 = 0; k0 < HH; k0 += 32) {
        if (k0) __syncthreads();
        write_l();
        __syncthreads();
        if (k0 + 32 < HH) load_g(k0 + 32);  // prefetch next tile over compute

        short8v wf[12];
        #pragma unroll
        for (int p = 0; p < 12; p++) wf[p] = *(const short8v*)&lds[woff[p]];
        #pragma unroll
        for (int m = 0; m < 4; m++) {
            short8v hh = *(const short8v*)&lds[8192 + aoff[m]];
            short8v hl = *(const short8v*)&lds[12288 + aoff[m]];
            accR[m]  = MFMA16(hh, wf[3],  accR[m]);
            accR[m]  = MFMA16(hh, wf[9],  accR[m]);
            accR[m]  = MFMA16(hl, wf[3],  accR[m]);
            accZ[m]  = MFMA16(hh, wf[4],  accZ[m]);
            accZ[m]  = MFMA16(hh, wf[10], accZ[m]);
            accZ[m]  = MFMA16(hl, wf[4],  accZ[m]);
            accNh[m] = MFMA16(hh, wf[5],  accNh[m]);
            accNh[m] = MFMA16(hh, wf[11], accNh[m]);
            accNh[m] = MFMA16(hl, wf[5],  accNh[m]);
            if (XMODE != 1) {
                short8v xh = *(const short8v*)&lds[aoff[m]];
                short8v xl = *(const short8v*)&lds[4096 + aoff[m]];
                accR[m]  = MFMA16(xh, wf[0], accR[m]);
                accR[m]  = MFMA16(xh, wf[6], accR[m]);
                accR[m]  = MFMA16(xl, wf[0], accR[m]);
                accZ[m]  = MFMA16(xh, wf[1], accZ[m]);
                accZ[m]  = MFMA16(xh, wf[7], accZ[m]);
                accZ[m]  = MFMA16(xl, wf[1], accZ[m]);
                accNi[m] = MFMA16(xh, wf[2], accNi[m]);
                accNi[m] = MFMA16(xh, wf[8], accNi[m]);
                accNi[m] = MFMA16(xl, wf[2], accNi[m]);
            }
        }
    }

    // ---- epilogue: GRU nonlinearity; C/D layout col=lane&15, row=kg*4+reg ----
    const int j = colBase + fj;
    const float br  = bih[j] + bhh[j];
    const float bz  = bih[HH + j] + bhh[HH + j];
    const float bni = bih[2 * HH + j];
    const float bnh = bhh[2 * HH + j];
    #pragma unroll
    for (int m = 0; m < 4; m++) {
        #pragma unroll
        for (int r = 0; r < 4; r++) {
            int b = rowBase + wr * 64 + m * 16 + kg * 4 + r;
            size_t idx = (size_t)b * HH + j;
            float rr = 1.f / (1.f + __expf(-(accR[m][r] + br)));
            float zz = 1.f / (1.f + __expf(-(accZ[m][r] + bz)));
            float nn = tanhf(accNi[m][r] + bni + rr * (accNh[m][r] + bnh));
            float hp = bf2f(Hin[idx]) + bf2f(Hin[BHs + idx]);
            float h = (1.f - zz) * nn + zz * hp;
            u16 hb = f2bf(h);
            Hout[idx] = hb;
            Hout[BHs + idx] = f2bf(h - bf2f(hb));
        }
    }
}

// ---------------------------------------------------------------------------
// Split-bf16 MFMA GEMM for logits: out[b*rstride + j] = h3 . Wout[j] + bias.
// A = h pair [4096,512], W = [512,512] hi/lo. Tile 128x64, grid (32,8), 8 waves.
// LDS (u16): A_hi[0) A_lo[4096) W_hi[8192) W_lo[10240), 24 KiB.
// ---------------------------------------------------------------------------
__global__ __launch_bounds__(512, 2) void k_outmm(
    const u16* __restrict__ Apair,
    const u16* __restrict__ Whi, const u16* __restrict__ Wlo,
    const float* __restrict__ bias,
    float* __restrict__ out, long rstride)
{
    const int tid = threadIdx.x;
    const int lane = tid & 63;
    const int wid = tid >> 6;
    const int wr = wid >> 2;
    const int wc = wid & 3;
    const int rowBase = blockIdx.x * 128;
    const int colBase = blockIdx.y * 64;

    __shared__ u16 lds[12288];

    const int srow = tid >> 2;
    const int sch = tid & 3;
    const int aoff_s = srow * 32 + ((sch ^ ((srow >> 1) & 3)) * 8);
    const u16* asrc_h = Apair + (size_t)(rowBase + srow) * HH + sch * 8;
    const u16* asrc_l = asrc_h + BHs;

    const int wt = tid & 255;
    const int wjr = wt >> 2;
    const int wch = wt & 3;
    const u16* wsrc1 = ((tid < 256) ? Whi : Wlo) + (size_t)(colBase + wjr) * HH + wch * 8;
    const int wdst1 = ((tid < 256) ? 8192 : 10240) + wjr * 32 +
                      ((wch ^ ((wjr >> 1) & 3)) * 8);

    const int fcol = lane & 15;
    const int kg = lane >> 4;
    const int fj = wc * 16 + fcol;
    const int woff_h = 8192 + fj * 32 + ((kg ^ ((fj >> 1) & 3)) * 8);
    const int woff_l = woff_h + 2048;
    int aoff[4];
    #pragma unroll
    for (int m = 0; m < 4; m++) {
        int r = wr * 64 + m * 16 + fcol;
        aoff[m] = r * 32 + ((kg ^ ((r >> 1) & 3)) * 8);
    }

    f32x4 acc[4];
    #pragma unroll
    for (int m = 0; m < 4; m++) acc[m] = (f32x4){0.f, 0.f, 0.f, 0.f};

    short8v rah, ral, rwv;
    auto load_g = [&](int K0) {
        rah = *(const short8v*)(asrc_h + K0);
        ral = *(const short8v*)(asrc_l + K0);
        rwv = *(const short8v*)(wsrc1 + K0);
    };
    load_g(0);
    for (int k0 = 0; k0 < HH; k0 += 32) {
        if (k0) __syncthreads();
        *(short8v*)&lds[aoff_s] = rah;
        *(short8v*)&lds[4096 + aoff_s] = ral;
        *(short8v*)&lds[wdst1] = rwv;
        __syncthreads();
        if (k0 + 32 < HH) load_g(k0 + 32);

        short8v wfh = *(const short8v*)&lds[woff_h];
        short8v wfl = *(const short8v*)&lds[woff_l];
        #pragma unroll
        for (int m = 0; m < 4; m++) {
            short8v ah = *(const short8v*)&lds[aoff[m]];
            short8v al = *(const short8v*)&lds[4096 + aoff[m]];
            acc[m] = MFMA16(ah, wfh, acc[m]);
            acc[m] = MFMA16(ah, wfl, acc[m]);
            acc[m] = MFMA16(al, wfh, acc[m]);
        }
    }

    const int j = colBase + fj;
    const float bb = bias[j];
    #pragma unroll
    for (int m = 0; m < 4; m++) {
        #pragma unroll
        for (int r = 0; r < 4; r++) {
            int b = rowBase + wr * 64 + m * 16 + kg * 4 + r;
            out[(long)b * rstride + j] = acc[m][r] + bb;
        }
    }
}

// ---------------------------------------------------------------------------
// reward / done heads: one wave per batch row; h3 is a bf16 hi/lo pair.
// ---------------------------------------------------------------------------
__global__ __launch_bounds__(256) void k_heads(
    const u16* __restrict__ h3,
    const float* __restrict__ Wr, const float* __restrict__ br,
    const float* __restrict__ Wd, const float* __restrict__ bd,
    float* __restrict__ out_r, float* __restrict__ out_d)
{
    int wave = threadIdx.x >> 6;
    int lane = threadIdx.x & 63;
    int b = blockIdx.x * 4 + wave;
    const short8v vh = *(const short8v*)(h3 + (size_t)b * HH + lane * 8);
    const short8v vl = *(const short8v*)(h3 + BHs + (size_t)b * HH + lane * 8);
    float sr = 0.f, sd = 0.f;
    #pragma unroll
    for (int i = 0; i < 8; i++) {
        float hv = bf2f_s(vh[i]) + bf2f_s(vl[i]);
        sr += hv * Wr[lane * 8 + i];
        sd += hv * Wd[lane * 8 + i];
    }
    #pragma unroll
    for (int off = 32; off > 0; off >>= 1) {
        sr += __shfl_xor(sr, off, 64);
        sd += __shfl_xor(sd, off, 64);
    }
    if (lane == 0) {
        out_r[b] = sr + br[0];
        out_d[b] = sd + bd[0];
    }
}

// hi/lo pair -> fp32 (final hidden output), 8 elems/thread
__global__ __launch_bounds__(256) void k_fh(const u16* __restrict__ pair,
                                            float* __restrict__ out)
{
    size_t i = ((size_t)blockIdx.x * 256 + threadIdx.x) * 8;
    short8v h = *(const short8v*)(pair + i);
    short8v l = *(const short8v*)(pair + BHs + i);
    float4 o0, o1;
    o0.x = bf2f_s(h[0]) + bf2f_s(l[0]); o0.y = bf2f_s(h[1]) + bf2f_s(l[1]);
    o0.z = bf2f_s(h[2]) + bf2f_s(l[2]); o0.w = bf2f_s(h[3]) + bf2f_s(l[3]);
    o1.x = bf2f_s(h[4]) + bf2f_s(l[4]); o1.y = bf2f_s(h[5]) + bf2f_s(l[5]);
    o1.z = bf2f_s(h[6]) + bf2f_s(l[6]); o1.w = bf2f_s(h[7]) + bf2f_s(l[7]);
    *(float4*)(out + i) = o0;
    *(float4*)(out + i + 4) = o1;
}

// ---------------------------------------------------------------------------
extern "C" void kernel_launch(void* const* d_in, const int* in_sizes, int n_in,
                              void* d_out, int out_size, void* d_ws, size_t ws_size,
                              hipStream_t stream)
{
    const float* action      = (const float*)d_in[0];
    const float* prev_hidden = (const float*)d_in[1];
    const int*   gt          = (const int*)d_in[2];
    const float* W_a   = (const float*)d_in[3];
    const float* b_a   = (const float*)d_in[4];
    const float* emb   = (const float*)d_in[5];
    const float* W_tp  = (const float*)d_in[6];
    const float* b_tp  = (const float*)d_in[7];
    const float* W_ih  = (const float*)d_in[8];
    const float* W_hh  = (const float*)d_in[9];
    const float* b_ih  = (const float*)d_in[10];
    const float* b_hh  = (const float*)d_in[11];
    const float* W_out = (const float*)d_in[12];
    const float* b_out = (const float*)d_in[13];
    const float* W_r   = (const float*)d_in[14];
    const float* b_r   = (const float*)d_in[15];
    const float* W_d   = (const float*)d_in[16];
    const float* b_d   = (const float*)d_in[17];

    // ---- fp32 output layout (verified r6) ----
    float* of       = (float*)d_out;
    float* o_logits = of;                          // B*T*C
    float* o_rew    = of + (size_t)BB * TT * 512;  // B
    float* o_done   = o_rew + BB;                  // B
    float* o_fh     = o_done + BB;                 // L*B*H

    // ---- workspace (u16 units): 72.35 MB total ----
    const size_t NW = (size_t)LL * 3 * HH * HH;    // 2,359,296 per array
    const size_t WL = (size_t)3 * HH * HH;         // per-layer stride
    u16* ws      = (u16*)d_ws;
    u16* Wih_hi  = ws;
    u16* Wih_lo  = Wih_hi + NW;
    u16* Whh_hi  = Wih_lo + NW;
    u16* Whh_lo  = Whh_hi + NW;
    u16* Wout_hi = Whh_lo + NW;
    u16* Wout_lo = Wout_hi + (size_t)512 * 512;
    u16* P_hi    = Wout_lo + (size_t)512 * 512;
    u16* P_lo    = P_hi + (size_t)512 * 512;
    u16* hbase   = P_lo + (size_t)512 * 512;       // 6 pair buffers, 2*BH each
    float* Pf    = (float*)(hbase + (size_t)6 * 2 * BHs);  // 512x512 fp32 scratch

    auto hbuf = [&](int l, int par) -> u16* {
        return hbase + (size_t)(l * 2 + par) * 2 * BHs;
    };

    // ---- one-time per launch: weight splits, P table, prev_hidden split ----
    k_split<<<2304, 256, 0, stream>>>(W_ih, Wih_hi, Wih_lo);
    k_split<<<2304, 256, 0, stream>>>(W_hh, Whh_hi, Whh_lo);
    k_split<<<256, 256, 0, stream>>>(W_out, Wout_hi, Wout_lo);
    for (int l = 0; l < LL; l++)
        k_split<<<2048, 256, 0, stream>>>(prev_hidden + (size_t)l * BHs,
                                          hbuf(l, 0), hbuf(l, 0) + BHs);
    v_gemm<<<dim3(8, 8), 256, 0, stream>>>(emb, W_tp, b_tp, Pf, 512);
    k_split<<<256, 256, 0, stream>>>(Pf, P_hi, P_lo);

    // ---- 17 sequential GRU-stack steps ----
    const dim3 g(32, 8);
    for (int s = 0; s <= 16; s++) {
        const int pi = s & 1, po = pi ^ 1;
        for (int l = 0; l < LL; l++) {
            const u16* wihh = Wih_hi + (size_t)l * WL;
            const u16* wihl = Wih_lo + (size_t)l * WL;
            const u16* whhh = Whh_hi + (size_t)l * WL;
            const u16* whhl = Whh_lo + (size_t)l * WL;
            const float* bi = b_ih + (size_t)l * 3 * HH;
            const float* bh = b_hh + (size_t)l * 3 * HH;
            const u16* Hin = hbuf(l, pi);
            u16* Ho = hbuf(l, po);
            if (l > 0) {
                const u16* Xp = hbuf(l - 1, po);
                k_cell<0><<<g, 512, 0, stream>>>(Xp, Xp + BHs, nullptr, 0,
                    nullptr, nullptr, nullptr, wihh, wihl, whhh, whhl,
                    bi, bh, Hin, Ho);
            } else if (s == 0) {
                k_cell<3><<<g, 512, 0, stream>>>(nullptr, nullptr, nullptr, 0,
                    action, W_a, b_a, wihh, wihl, whhh, whhl, bi, bh, Hin, Ho);
            } else if (s == 1) {
                k_cell<1><<<g, 512, 0, stream>>>(nullptr, nullptr, nullptr, 0,
                    nullptr, nullptr, nullptr, wihh, wihl, whhh, whhl,
                    bi, bh, Hin, Ho);
            } else {
                k_cell<2><<<g, 512, 0, stream>>>(P_hi, P_lo, gt, s - 2,
                    nullptr, nullptr, nullptr, wihh, wihl, whhh, whhl,
                    bi, bh, Hin, Ho);
            }
        }
        if (s == 0) {
            k_heads<<<BB / 4, 256, 0, stream>>>(hbuf(2, po), W_r, b_r, W_d, b_d,
                                                o_rew, o_done);
        } else {
            k_outmm<<<g, 512, 0, stream>>>(hbuf(2, po), Wout_hi, Wout_lo, b_out,
                o_logits + (size_t)(s - 1) * 512, (long)TT * 512);
        }
    }

    // ---- final hidden stack (parity after s=16 is 1) -> fp32 output ----
    for (int l = 0; l < LL; l++)
        k_fh<<<1024, 256, 0, stream>>>(hbuf(l, 1), o_fh + (size_t)l * BHs);
}